// Round 5
// baseline (1053.427 us; speedup 1.0000x reference)
//
#include <hip/hip_runtime.h>
#include <math.h>

// GraphCNN v5:
//  - bucketed 2-phase CSR build: bin by col>>8 into contiguous CSR regions with
//    per-bucket cursors (line-coalesced writes, ~payload WRITE_SIZE), then place
//    within-bucket via LDS per-node cursors. Dual: by-col {src,eid} + by-row {eid}.
//  - k_eembed fuses edge-embed col+row gathers with the 16->64 GEMM + dis
//    (replaces k_egc + k_eaggrow(19.2M atomics) + k_edgemm).
// Packing assumes N < 2^17, E < 2^24 (here N=1e5, E=1.2e6).

// ---------------- node embed: h0 = x @ node_w + node_b  (K=128) ----------------
__global__ __launch_bounds__(256) void k_embed(
    const float* __restrict__ x, const float* __restrict__ w,
    const float* __restrict__ b, float* __restrict__ out, int N) {
  __shared__ __align__(16) float in_lds[64 * 132];
  const int base = blockIdx.x * 64;
  const int t = threadIdx.x;
#pragma unroll
  for (int it = 0; it < 32; ++it) {
    int lin = t + it * 256;
    int r = lin >> 7, c = lin & 127;
    int row = base + r;
    in_lds[r * 132 + c] = (row < N) ? x[(size_t)row * 128 + c] : 0.f;
  }
  __syncthreads();
  const int j = t & 63;
  const int wv = __builtin_amdgcn_readfirstlane(t >> 6);
  const float* wp = w + wv * 16;
  float acc[16];
#pragma unroll
  for (int c = 0; c < 16; ++c) acc[c] = 0.f;
#pragma unroll
  for (int k4 = 0; k4 < 32; ++k4) {
    float4 a = *(const float4*)&in_lds[j * 132 + k4 * 4];
#pragma unroll
    for (int kk = 0; kk < 4; ++kk) {
      float av = ((const float*)&a)[kk];
      int k = k4 * 4 + kk;
#pragma unroll
      for (int c = 0; c < 16; ++c)
        acc[c] = fmaf(av, wp[k * 64 + c], acc[c]);
    }
  }
  int row = base + j;
  if (row < N) {
#pragma unroll
    for (int c4 = 0; c4 < 4; ++c4) {
      float4 o;
#pragma unroll
      for (int q = 0; q < 4; ++q)
        ((float*)&o)[q] = acc[c4 * 4 + q] + b[wv * 16 + c4 * 4 + q];
      *(float4*)&out[(size_t)row * 64 + wv * 16 + c4 * 4] = o;
    }
  }
}

// ------- degree counts -------
__global__ __launch_bounds__(256) void k_count(
    const int* __restrict__ erow, const int* __restrict__ ecol,
    int* indeg, int* outdeg, int E) {
  int e = blockIdx.x * 256 + threadIdx.x;
  if (e < E) {
    atomicAdd(&indeg[ecol[e]], 1);
    atomicAdd(&outdeg[erow[e]], 1);
  }
}

// ------- exclusive scan (3 kernels, chunk=1024) -------
__global__ __launch_bounds__(256) void k_scanA(
    const int* __restrict__ cnt, int* __restrict__ off,
    int* __restrict__ chunk_sum, int N) {
  __shared__ int sc[256];
  int b = blockIdx.x, t = threadIdx.x;
  int i0 = b * 1024 + t * 4;
  int v[4];
  int s = 0;
#pragma unroll
  for (int q = 0; q < 4; ++q) {
    v[q] = (i0 + q < N) ? cnt[i0 + q] : 0;
    s += v[q];
  }
  sc[t] = s;
  __syncthreads();
  for (int d = 1; d < 256; d <<= 1) {
    int x = (t >= d) ? sc[t - d] : 0;
    __syncthreads();
    sc[t] += x;
    __syncthreads();
  }
  int run = sc[t] - s;
#pragma unroll
  for (int q = 0; q < 4; ++q) {
    if (i0 + q < N) off[i0 + q] = run;
    run += v[q];
  }
  if (t == 255) chunk_sum[b] = sc[255];
}

__global__ __launch_bounds__(128) void k_scanB(
    const int* __restrict__ chunk_sum, int* __restrict__ chunk_base, int nch) {
  __shared__ int sc[128];
  int t = threadIdx.x;
  int s = (t < nch) ? chunk_sum[t] : 0;
  sc[t] = s;
  __syncthreads();
  for (int d = 1; d < 128; d <<= 1) {
    int x = (t >= d) ? sc[t - d] : 0;
    __syncthreads();
    sc[t] += x;
    __syncthreads();
  }
  if (t < nch) chunk_base[t] = sc[t] - s;
}

__global__ __launch_bounds__(256) void k_scanC(
    int* __restrict__ off, const int* __restrict__ chunk_base, int N) {
  int i = blockIdx.x * 256 + threadIdx.x;
  if (i < N) off[i] += chunk_base[i >> 10];
}

// ------- bucket cursor init: bucket start = node-CSR offset of first node -------
__global__ __launch_bounds__(256) void k_binit(
    const int* __restrict__ offc, const int* __restrict__ offr,
    int* __restrict__ bcur_c, int* __restrict__ bcur_r, int NB) {
  int b = blockIdx.x * 256 + threadIdx.x;
  if (b < NB) {
    bcur_c[b] = offc[b << 8];
    bcur_r[b] = offr[b << 8];
  }
}

// ------- bin: write packed entries into contiguous bucket regions -------
__global__ __launch_bounds__(256) void k_bin(
    const int* __restrict__ erow, const int* __restrict__ ecol,
    int* bcur_c, int* bcur_r,
    unsigned long long* __restrict__ tmpc, unsigned int* __restrict__ tmpr, int E) {
  int e = blockIdx.x * 256 + threadIdx.x;
  if (e >= E) return;
  int r = erow[e], c = ecol[e];
  int pc = atomicAdd(&bcur_c[c >> 8], 1);
  tmpc[pc] = (unsigned long long)(c & 255) |
             ((unsigned long long)r << 8) |
             ((unsigned long long)e << 25);
  int pr = atomicAdd(&bcur_r[r >> 8], 1);
  tmpr[pr] = ((unsigned int)e << 8) | (unsigned int)(r & 255);
}

// ------- place by-col: ordered CSR {src, eid} via LDS per-node cursors -------
__global__ __launch_bounds__(256) void k_place_c(
    const unsigned long long* __restrict__ tmpc, const int* __restrict__ offc,
    int2* __restrict__ lst2, int N, int E) {
  __shared__ int cur[256];
  int b = blockIdx.x, t = threadIdx.x;
  int colbase = b << 8;
  int nb = min(256, N - colbase);
  if (t < nb) cur[t] = offc[colbase + t];
  __syncthreads();
  int bstart = offc[colbase];
  int bend = (colbase + 256 < N) ? offc[colbase + 256] : E;
  for (int idx = bstart + t; idx < bend; idx += 256) {
    unsigned long long v = tmpc[idx];
    int lc = (int)(v & 255);
    int src = (int)((v >> 8) & 0x1FFFF);
    int eid = (int)(v >> 25);
    int p = atomicAdd(&cur[lc], 1);
    int2 w; w.x = src; w.y = eid;
    lst2[p] = w;
  }
}

// ------- place by-row: eid list grouped by row -------
__global__ __launch_bounds__(256) void k_place_r(
    const unsigned int* __restrict__ tmpr, const int* __restrict__ offr,
    int* __restrict__ eidr, int N, int E) {
  __shared__ int cur[256];
  int b = blockIdx.x, t = threadIdx.x;
  int rowbase = b << 8;
  int nb = min(256, N - rowbase);
  if (t < nb) cur[t] = offr[rowbase + t];
  __syncthreads();
  int bstart = offr[rowbase];
  int bend = (rowbase + 256 < N) ? offr[rowbase + 256] : E;
  for (int idx = bstart + t; idx < bend; idx += 256) {
    unsigned int v = tmpr[idx];
    int lr = (int)(v & 255);
    int p = atomicAdd(&cur[lr], 1);
    eidr[p] = (int)(v >> 8);
  }
}

// ------- fused edge embed: gather ea over incident edges (col via lst2.y,
//         row via eidr), reduce, then h0 += acc16 @ ew + (id+od)*eb ; dis -------
__global__ __launch_bounds__(256) void k_eembed(
    const float* __restrict__ ea, const int2* __restrict__ lst2,
    const int* __restrict__ eidr, const int* __restrict__ offc,
    const int* __restrict__ indeg, const int* __restrict__ offr,
    const int* __restrict__ outdeg, const float* __restrict__ ew,
    const float* __restrict__ eb, float* h0, float* __restrict__ dis, int N) {
  int t = blockIdx.x * 256 + threadIdx.x;
  int n = __builtin_amdgcn_readfirstlane(t >> 6);
  if (n >= N) return;
  int lane = threadIdx.x & 63;
  int slot = lane >> 4, kk = lane & 15;
  int cin = indeg[n], basec = offc[n];
  int cout = outdeg[n], baser = offr[n];
  float acc = 0.f;
  int c0 = (cin > 0) ? cin - 1 : 0;
  for (int i = 0; i < cin; i += 16) {
#pragma unroll
    for (int q = 0; q < 4; ++q) {
      int idx = i + q * 4 + slot;
      int eid = lst2[basec + min(idx, c0)].y;
      float v = ea[(size_t)eid * 16 + kk];
      acc += (idx < cin) ? v : 0.f;
    }
  }
  int r0 = (cout > 0) ? cout - 1 : 0;
  for (int i = 0; i < cout; i += 16) {
#pragma unroll
    for (int q = 0; q < 4; ++q) {
      int idx = i + q * 4 + slot;
      int eid = eidr[baser + min(idx, r0)];
      float v = ea[(size_t)eid * 16 + kk];
      acc += (idx < cout) ? v : 0.f;
    }
  }
  acc += __shfl_xor(acc, 16, 64);
  acc += __shfl_xor(acc, 32, 64);  // all lanes now hold total for their kk
  int j = lane;
  float v = h0[(size_t)n * 64 + j] + (float)(cin + cout) * eb[j];
#pragma unroll
  for (int k = 0; k < 16; ++k) {
    float ak = __shfl(acc, k, 64);
    v = fmaf(ak, ew[k * 64 + j], v);
  }
  h0[(size_t)n * 64 + j] = v;
  if (j == 0) dis[n] = 1.0f / sqrtf((float)cin + 1.0f);
}

// ------- conv GEMM with dis-prescale: xws = dis * (h @ w) -------
__global__ __launch_bounds__(256) void k_conv(
    const float* __restrict__ hin, const float* __restrict__ w,
    const float* __restrict__ dis, float* __restrict__ xws, int N) {
  __shared__ __align__(16) float in_lds[64 * 68];
  const int base = blockIdx.x * 64;
  const int t = threadIdx.x;
#pragma unroll
  for (int it = 0; it < 16; ++it) {
    int lin = t + it * 256;
    int r = lin >> 6, c = lin & 63;
    int row = base + r;
    in_lds[r * 68 + c] = (row < N) ? hin[(size_t)row * 64 + c] : 0.f;
  }
  __syncthreads();
  const int j = t & 63;
  const int wv = __builtin_amdgcn_readfirstlane(t >> 6);
  const float* wp = w + wv * 16;
  float acc[16];
#pragma unroll
  for (int c = 0; c < 16; ++c) acc[c] = 0.f;
#pragma unroll
  for (int k4 = 0; k4 < 16; ++k4) {
    float4 a = *(const float4*)&in_lds[j * 68 + k4 * 4];
#pragma unroll
    for (int kk = 0; kk < 4; ++kk) {
      float av = ((const float*)&a)[kk];
      int k = k4 * 4 + kk;
#pragma unroll
      for (int c = 0; c < 16; ++c)
        acc[c] = fmaf(av, wp[k * 64 + c], acc[c]);
    }
  }
  int row = base + j;
  if (row < N) {
    float d = dis[row];
#pragma unroll
    for (int c4 = 0; c4 < 4; ++c4) {
      float4 o;
#pragma unroll
      for (int q = 0; q < 4; ++q)
        ((float*)&o)[q] = d * acc[c4 * 4 + q];
      *(float4*)&xws[(size_t)row * 64 + wv * 16 + c4 * 4] = o;
    }
  }
}

// ------- gather: h_new = relu( dis_n * (xws[n] + sum_src xws[src]) + b ) -------
__global__ __launch_bounds__(256) void k_gather(
    const float* __restrict__ xws, const float* __restrict__ dis,
    const int* __restrict__ offc, const int* __restrict__ indeg,
    const int2* __restrict__ lst2, const float* __restrict__ b,
    float* __restrict__ h0, float* __restrict__ hj_slice, int N) {
  int t = blockIdx.x * 256 + threadIdx.x;
  int j = t & 63;
  int n = __builtin_amdgcn_readfirstlane(t >> 6);
  if (n >= N) return;
  int cnt = indeg[n];
  int base = offc[n];
  int c0 = (cnt > 0) ? cnt - 1 : 0;
  float acc = xws[(size_t)n * 64 + j];
  for (int i = 0; i < cnt; i += 16) {
    float s[16];
#pragma unroll
    for (int q = 0; q < 16; ++q) {
      int src = lst2[base + min(i + q, c0)].x;
      s[q] = xws[(size_t)src * 64 + j];
    }
#pragma unroll
    for (int q = 0; q < 16; ++q)
      acc += (i + q < cnt) ? s[q] : 0.f;
  }
  float act = fmaxf(fmaf(dis[n], acc, b[j]), 0.f);
  h0[(size_t)n * 64 + j] = act;
  hj_slice[(size_t)n * 192 + j] = act;
}

// ------- mean-pool (batch sorted -> binary search) + classifier -------
__global__ __launch_bounds__(192) void k_pool(
    const float* __restrict__ hj, const int* __restrict__ batch, int N,
    const float* __restrict__ w1, const float* __restrict__ b1,
    const float* __restrict__ w2, const float* __restrict__ b2,
    float* __restrict__ out) {
  __shared__ float pl[192];
  int g = blockIdx.x;
  int t = threadIdx.x;
  int lo = 0, hi = N;
  while (lo < hi) { int m = (lo + hi) >> 1; if (batch[m] < g) lo = m + 1; else hi = m; }
  int start = lo;
  hi = N;
  while (lo < hi) { int m = (lo + hi) >> 1; if (batch[m] < g + 1) lo = m + 1; else hi = m; }
  int end = lo;
  float s = 0.f;
  for (int r = start; r < end; ++r) s += hj[(size_t)r * 192 + t];
  int cnt = end - start;
  pl[t] = s / (float)(cnt > 0 ? cnt : 1);
  __syncthreads();
  if (t < 64) {
    float val = 0.f;
    if (t < 32) {
      float z = b1[t];
#pragma unroll 8
      for (int k = 0; k < 192; ++k) z = fmaf(pl[k], w1[k * 32 + t], z);
      z = fmaxf(z, 0.f);
      val = z * w2[t];
    }
#pragma unroll
    for (int off = 16; off > 0; off >>= 1) val += __shfl_down(val, off);
    if (t == 0) out[g] = val + b2[0];
  }
}

extern "C" void kernel_launch(void* const* d_in, const int* in_sizes, int n_in,
                              void* d_out, int out_size, void* d_ws, size_t ws_size,
                              hipStream_t stream) {
  const float* x      = (const float*)d_in[0];
  const float* ea     = (const float*)d_in[1];
  const float* node_w = (const float*)d_in[2];
  const float* node_b = (const float*)d_in[3];
  const float* edge_w = (const float*)d_in[4];
  const float* edge_b = (const float*)d_in[5];
  const float* conv_w = (const float*)d_in[6];
  const float* conv_b = (const float*)d_in[7];
  const float* w1     = (const float*)d_in[8];
  const float* b1     = (const float*)d_in[9];
  const float* w2     = (const float*)d_in[10];
  const float* b2     = (const float*)d_in[11];
  const int*   ei     = (const int*)d_in[12];
  const int*   batch  = (const int*)d_in[13];

  const int N = in_sizes[0] / 128;
  const int E = in_sizes[12] / 2;
  const int G = out_size;
  const int* erow = ei;
  const int* ecol = ei + E;

  float* ws = (float*)d_ws;
  size_t o = 0;
  float* h0    = ws + o; o += (size_t)N * 64;
  float* xws   = ws + o; o += (size_t)N * 64;
  float* hj    = ws + o; o += (size_t)N * 192;  // tmpc/tmpr/eidr alias its head
  float* dis   = ws + o; o += N;
  int* indeg   = (int*)(ws + o); o += N;
  int* outdeg  = (int*)(ws + o); o += N;
  int* offc    = (int*)(ws + o); o += N;
  int* offr    = (int*)(ws + o); o += N;
  int* chsum   = (int*)(ws + o); o += 128;
  int* chbase  = (int*)(ws + o); o += 128;
  int2* lst2   = (int2*)(ws + o); o += (size_t)2 * E;
  const int NB = (N + 255) >> 8;
  int* bcur_c  = (int*)(ws + o); o += NB;
  int* bcur_r  = (int*)(ws + o); o += NB;
  // aliases onto hj (dead before first k_gather writes hj):
  unsigned long long* tmpc = (unsigned long long*)hj;          // E * 8B
  unsigned int* tmpr = (unsigned int*)(hj + (size_t)2 * E);    // E * 4B
  int* eidr          = (int*)(hj + (size_t)3 * E);             // E * 4B
  float* out = (float*)d_out;

  const int nch = (N + 1023) / 1024;
  dim3 b256(256);

  hipMemsetAsync(indeg, 0, (size_t)N * sizeof(int), stream);
  hipMemsetAsync(outdeg, 0, (size_t)N * sizeof(int), stream);

  k_embed<<<(N + 63) / 64, b256, 0, stream>>>(x, node_w, node_b, h0, N);
  k_count<<<(E + 255) / 256, b256, 0, stream>>>(erow, ecol, indeg, outdeg, E);
  k_scanA<<<nch, b256, 0, stream>>>(indeg, offc, chsum, N);
  k_scanB<<<1, dim3(128), 0, stream>>>(chsum, chbase, nch);
  k_scanC<<<(N + 255) / 256, b256, 0, stream>>>(offc, chbase, N);
  k_scanA<<<nch, b256, 0, stream>>>(outdeg, offr, chsum, N);
  k_scanB<<<1, dim3(128), 0, stream>>>(chsum, chbase, nch);
  k_scanC<<<(N + 255) / 256, b256, 0, stream>>>(offr, chbase, N);
  k_binit<<<(NB + 255) / 256, b256, 0, stream>>>(offc, offr, bcur_c, bcur_r, NB);
  k_bin<<<(E + 255) / 256, b256, 0, stream>>>(erow, ecol, bcur_c, bcur_r,
                                              tmpc, tmpr, E);
  k_place_c<<<NB, b256, 0, stream>>>(tmpc, offc, lst2, N, E);
  k_place_r<<<NB, b256, 0, stream>>>(tmpr, offr, eidr, N, E);
  k_eembed<<<((size_t)N * 64 + 255) / 256, b256, 0, stream>>>(
      ea, lst2, eidr, offc, indeg, offr, outdeg, edge_w, edge_b, h0, dis, N);
  for (int l = 0; l < 3; ++l) {
    k_conv<<<(N + 63) / 64, b256, 0, stream>>>(
        h0, conv_w + (size_t)l * 64 * 64, dis, xws, N);
    k_gather<<<((size_t)N * 64 + 255) / 256, b256, 0, stream>>>(
        xws, dis, offc, indeg, lst2, conv_b + (size_t)l * 64,
        h0, hj + (size_t)l * 64, N);
  }
  k_pool<<<G, dim3(192), 0, stream>>>(hj, batch, N, w1, b1, w2, b2, out);
}

// Round 6
// 708.551 us; speedup vs baseline: 1.4867x; 1.4867x over previous
//
#include <hip/hip_runtime.h>
#include <math.h>

// GraphCNN v6: contention-free CSR build.
//  v5 lesson: 2.4M global atomics over ~780 cursors = 537us (cross-XCD
//  serialization). v6 builds per-(block,bucket) write ranges via dense
//  histogram matrices + scans -> k_scat has ZERO global atomics and each
//  ~10-entry range is written by one block (line-coalesced).
//  Assumes N <= 131072 (NB <= 512 buckets), E < 2^24, N < 2^17.

#define EPB 4096  // edges per binning block (256 thr x 16)

// ---------------- node embed: h0 = x @ node_w + node_b  (K=128) ----------------
__global__ __launch_bounds__(256) void k_embed(
    const float* __restrict__ x, const float* __restrict__ w,
    const float* __restrict__ b, float* __restrict__ out, int N) {
  __shared__ __align__(16) float in_lds[64 * 132];
  const int base = blockIdx.x * 64;
  const int t = threadIdx.x;
#pragma unroll
  for (int it = 0; it < 32; ++it) {
    int lin = t + it * 256;
    int r = lin >> 7, c = lin & 127;
    int row = base + r;
    in_lds[r * 132 + c] = (row < N) ? x[(size_t)row * 128 + c] : 0.f;
  }
  __syncthreads();
  const int j = t & 63;
  const int wv = __builtin_amdgcn_readfirstlane(t >> 6);
  const float* wp = w + wv * 16;
  float acc[16];
#pragma unroll
  for (int c = 0; c < 16; ++c) acc[c] = 0.f;
#pragma unroll
  for (int k4 = 0; k4 < 32; ++k4) {
    float4 a = *(const float4*)&in_lds[j * 132 + k4 * 4];
#pragma unroll
    for (int kk = 0; kk < 4; ++kk) {
      float av = ((const float*)&a)[kk];
      int k = k4 * 4 + kk;
#pragma unroll
      for (int c = 0; c < 16; ++c)
        acc[c] = fmaf(av, wp[k * 64 + c], acc[c]);
    }
  }
  int row = base + j;
  if (row < N) {
#pragma unroll
    for (int c4 = 0; c4 < 4; ++c4) {
      float4 o;
#pragma unroll
      for (int q = 0; q < 4; ++q)
        ((float*)&o)[q] = acc[c4 * 4 + q] + b[wv * 16 + c4 * 4 + q];
      *(float4*)&out[(size_t)row * 64 + wv * 16 + c4 * 4] = o;
    }
  }
}

// ------- degree counts -------
__global__ __launch_bounds__(256) void k_count(
    const int* __restrict__ erow, const int* __restrict__ ecol,
    int* indeg, int* outdeg, int E) {
  int e = blockIdx.x * 256 + threadIdx.x;
  if (e < E) {
    atomicAdd(&indeg[ecol[e]], 1);
    atomicAdd(&outdeg[erow[e]], 1);
  }
}

// ------- exclusive scan (3 kernels, chunk=1024) -------
__global__ __launch_bounds__(256) void k_scanA(
    const int* __restrict__ cnt, int* __restrict__ off,
    int* __restrict__ chunk_sum, int N) {
  __shared__ int sc[256];
  int b = blockIdx.x, t = threadIdx.x;
  int i0 = b * 1024 + t * 4;
  int v[4];
  int s = 0;
#pragma unroll
  for (int q = 0; q < 4; ++q) {
    v[q] = (i0 + q < N) ? cnt[i0 + q] : 0;
    s += v[q];
  }
  sc[t] = s;
  __syncthreads();
  for (int d = 1; d < 256; d <<= 1) {
    int x = (t >= d) ? sc[t - d] : 0;
    __syncthreads();
    sc[t] += x;
    __syncthreads();
  }
  int run = sc[t] - s;
#pragma unroll
  for (int q = 0; q < 4; ++q) {
    if (i0 + q < N) off[i0 + q] = run;
    run += v[q];
  }
  if (t == 255) chunk_sum[b] = sc[255];
}

__global__ __launch_bounds__(128) void k_scanB(
    const int* __restrict__ chunk_sum, int* __restrict__ chunk_base, int nch) {
  __shared__ int sc[128];
  int t = threadIdx.x;
  int s = (t < nch) ? chunk_sum[t] : 0;
  sc[t] = s;
  __syncthreads();
  for (int d = 1; d < 128; d <<= 1) {
    int x = (t >= d) ? sc[t - d] : 0;
    __syncthreads();
    sc[t] += x;
    __syncthreads();
  }
  if (t < nch) chunk_base[t] = sc[t] - s;
}

__global__ __launch_bounds__(256) void k_scanC(
    int* __restrict__ off, const int* __restrict__ chunk_base, int N) {
  int i = blockIdx.x * 256 + threadIdx.x;
  if (i < N) off[i] += chunk_base[i >> 10];
}

// ------- per-block bucket histograms (block-major: mat[b*NB + bucket]) -------
__global__ __launch_bounds__(256) void k_hist(
    const int* __restrict__ erow, const int* __restrict__ ecol,
    int* __restrict__ matc, int* __restrict__ matr, int E, int NB) {
  __shared__ int hc[512], hr[512];
  int b = blockIdx.x, t = threadIdx.x;
  for (int i = t; i < NB; i += 256) { hc[i] = 0; hr[i] = 0; }
  __syncthreads();
  int e0 = b * EPB;
#pragma unroll
  for (int q = 0; q < 16; ++q) {
    int e = e0 + q * 256 + t;
    if (e < E) {
      atomicAdd(&hc[ecol[e] >> 8], 1);
      atomicAdd(&hr[erow[e] >> 8], 1);
    }
  }
  __syncthreads();
  for (int i = t; i < NB; i += 256) {
    matc[(size_t)b * NB + i] = hc[i];
    matr[(size_t)b * NB + i] = hr[i];
  }
}

// ------- column scan: mat[.][i] -> exclusive running sum; tot[i] = total -------
__global__ __launch_bounds__(256) void kB1(
    int* __restrict__ mat, int* __restrict__ tot, int NBLK, int NB) {
  int i = blockIdx.x * 256 + threadIdx.x;
  if (i >= NB) return;
  int run = 0;
  for (int b = 0; b < NBLK; ++b) {
    size_t idx = (size_t)b * NB + i;
    int v = mat[idx];
    mat[idx] = run;
    run += v;
  }
  tot[i] = run;
}

// ------- exclusive scan of bucket totals -> bucket starts (NB <= 512) -------
__global__ __launch_bounds__(512) void kB2(
    const int* __restrict__ tot, int* __restrict__ start, int NB) {
  __shared__ int sc[512];
  int t = threadIdx.x;
  int s = (t < NB) ? tot[t] : 0;
  sc[t] = s;
  __syncthreads();
  for (int d = 1; d < 512; d <<= 1) {
    int x = (t >= d) ? sc[t - d] : 0;
    __syncthreads();
    sc[t] += x;
    __syncthreads();
  }
  if (t < NB) start[t] = sc[t] - s;
}

// ------- scatter into bucket regions; LDS cursors, no global atomics -------
__global__ __launch_bounds__(256) void k_scat(
    const int* __restrict__ erow, const int* __restrict__ ecol,
    const int* __restrict__ matc, const int* __restrict__ matr,
    const int* __restrict__ startc, const int* __restrict__ startr,
    unsigned long long* __restrict__ tmpc, unsigned int* __restrict__ tmpr,
    int E, int NB) {
  __shared__ int curc[512], curr[512];
  int b = blockIdx.x, t = threadIdx.x;
  for (int i = t; i < NB; i += 256) {
    curc[i] = startc[i] + matc[(size_t)b * NB + i];
    curr[i] = startr[i] + matr[(size_t)b * NB + i];
  }
  __syncthreads();
  int e0 = b * EPB;
#pragma unroll
  for (int q = 0; q < 16; ++q) {
    int e = e0 + q * 256 + t;
    if (e < E) {
      int r = erow[e], c = ecol[e];
      int pc = atomicAdd(&curc[c >> 8], 1);
      tmpc[pc] = (unsigned long long)(c & 255) |
                 ((unsigned long long)r << 8) |
                 ((unsigned long long)e << 25);
      int pr = atomicAdd(&curr[r >> 8], 1);
      tmpr[pr] = ((unsigned int)e << 8) | (unsigned int)(r & 255);
    }
  }
}

// ------- place by-col: ordered CSR {src, eid} via LDS per-node cursors -------
__global__ __launch_bounds__(256) void k_place_c(
    const unsigned long long* __restrict__ tmpc, const int* __restrict__ offc,
    int2* __restrict__ lst2, int N, int E) {
  __shared__ int cur[256];
  int b = blockIdx.x, t = threadIdx.x;
  int colbase = b << 8;
  int nb = min(256, N - colbase);
  if (t < nb) cur[t] = offc[colbase + t];
  __syncthreads();
  int bstart = offc[colbase];
  int bend = (colbase + 256 < N) ? offc[colbase + 256] : E;
  for (int idx = bstart + t; idx < bend; idx += 256) {
    unsigned long long v = tmpc[idx];
    int lc = (int)(v & 255);
    int src = (int)((v >> 8) & 0x1FFFF);
    int eid = (int)(v >> 25);
    int p = atomicAdd(&cur[lc], 1);
    int2 w; w.x = src; w.y = eid;
    lst2[p] = w;
  }
}

// ------- place by-row: eid list grouped by row -------
__global__ __launch_bounds__(256) void k_place_r(
    const unsigned int* __restrict__ tmpr, const int* __restrict__ offr,
    int* __restrict__ eidr, int N, int E) {
  __shared__ int cur[256];
  int b = blockIdx.x, t = threadIdx.x;
  int rowbase = b << 8;
  int nb = min(256, N - rowbase);
  if (t < nb) cur[t] = offr[rowbase + t];
  __syncthreads();
  int bstart = offr[rowbase];
  int bend = (rowbase + 256 < N) ? offr[rowbase + 256] : E;
  for (int idx = bstart + t; idx < bend; idx += 256) {
    unsigned int v = tmpr[idx];
    int lr = (int)(v & 255);
    int p = atomicAdd(&cur[lr], 1);
    eidr[p] = (int)(v >> 8);
  }
}

// ------- fused edge embed: gather ea over incident edges (col via lst2.y,
//         row via eidr), reduce, then h0 += acc16 @ ew + (id+od)*eb ; dis -------
__global__ __launch_bounds__(256) void k_eembed(
    const float* __restrict__ ea, const int2* __restrict__ lst2,
    const int* __restrict__ eidr, const int* __restrict__ offc,
    const int* __restrict__ indeg, const int* __restrict__ offr,
    const int* __restrict__ outdeg, const float* __restrict__ ew,
    const float* __restrict__ eb, float* h0, float* __restrict__ dis, int N) {
  int t = blockIdx.x * 256 + threadIdx.x;
  int n = __builtin_amdgcn_readfirstlane(t >> 6);
  if (n >= N) return;
  int lane = threadIdx.x & 63;
  int slot = lane >> 4, kk = lane & 15;
  int cin = indeg[n], basec = offc[n];
  int cout = outdeg[n], baser = offr[n];
  float acc = 0.f;
  int c0 = (cin > 0) ? cin - 1 : 0;
  for (int i = 0; i < cin; i += 16) {
#pragma unroll
    for (int q = 0; q < 4; ++q) {
      int idx = i + q * 4 + slot;
      int eid = lst2[basec + min(idx, c0)].y;
      float v = ea[(size_t)eid * 16 + kk];
      acc += (idx < cin) ? v : 0.f;
    }
  }
  int r0 = (cout > 0) ? cout - 1 : 0;
  for (int i = 0; i < cout; i += 16) {
#pragma unroll
    for (int q = 0; q < 4; ++q) {
      int idx = i + q * 4 + slot;
      int eid = eidr[baser + min(idx, r0)];
      float v = ea[(size_t)eid * 16 + kk];
      acc += (idx < cout) ? v : 0.f;
    }
  }
  acc += __shfl_xor(acc, 16, 64);
  acc += __shfl_xor(acc, 32, 64);  // all lanes hold total for feature lane&15
  int j = lane;
  float v = h0[(size_t)n * 64 + j] + (float)(cin + cout) * eb[j];
#pragma unroll
  for (int k = 0; k < 16; ++k) {
    float ak = __shfl(acc, k, 64);
    v = fmaf(ak, ew[k * 64 + j], v);
  }
  h0[(size_t)n * 64 + j] = v;
  if (j == 0) dis[n] = 1.0f / sqrtf((float)cin + 1.0f);
}

// ------- conv GEMM with dis-prescale: xws = dis * (h @ w) -------
__global__ __launch_bounds__(256) void k_conv(
    const float* __restrict__ hin, const float* __restrict__ w,
    const float* __restrict__ dis, float* __restrict__ xws, int N) {
  __shared__ __align__(16) float in_lds[64 * 68];
  const int base = blockIdx.x * 64;
  const int t = threadIdx.x;
#pragma unroll
  for (int it = 0; it < 16; ++it) {
    int lin = t + it * 256;
    int r = lin >> 6, c = lin & 63;
    int row = base + r;
    in_lds[r * 68 + c] = (row < N) ? hin[(size_t)row * 64 + c] : 0.f;
  }
  __syncthreads();
  const int j = t & 63;
  const int wv = __builtin_amdgcn_readfirstlane(t >> 6);
  const float* wp = w + wv * 16;
  float acc[16];
#pragma unroll
  for (int c = 0; c < 16; ++c) acc[c] = 0.f;
#pragma unroll
  for (int k4 = 0; k4 < 16; ++k4) {
    float4 a = *(const float4*)&in_lds[j * 68 + k4 * 4];
#pragma unroll
    for (int kk = 0; kk < 4; ++kk) {
      float av = ((const float*)&a)[kk];
      int k = k4 * 4 + kk;
#pragma unroll
      for (int c = 0; c < 16; ++c)
        acc[c] = fmaf(av, wp[k * 64 + c], acc[c]);
    }
  }
  int row = base + j;
  if (row < N) {
    float d = dis[row];
#pragma unroll
    for (int c4 = 0; c4 < 4; ++c4) {
      float4 o;
#pragma unroll
      for (int q = 0; q < 4; ++q)
        ((float*)&o)[q] = d * acc[c4 * 4 + q];
      *(float4*)&xws[(size_t)row * 64 + wv * 16 + c4 * 4] = o;
    }
  }
}

// ------- gather: h_new = relu( dis_n * (xws[n] + sum_src xws[src]) + b ) -------
__global__ __launch_bounds__(256) void k_gather(
    const float* __restrict__ xws, const float* __restrict__ dis,
    const int* __restrict__ offc, const int* __restrict__ indeg,
    const int2* __restrict__ lst2, const float* __restrict__ b,
    float* __restrict__ h0, float* __restrict__ hj_slice, int N) {
  int t = blockIdx.x * 256 + threadIdx.x;
  int j = t & 63;
  int n = __builtin_amdgcn_readfirstlane(t >> 6);
  if (n >= N) return;
  int cnt = indeg[n];
  int base = offc[n];
  int c0 = (cnt > 0) ? cnt - 1 : 0;
  float acc = xws[(size_t)n * 64 + j];
  for (int i = 0; i < cnt; i += 16) {
    float s[16];
#pragma unroll
    for (int q = 0; q < 16; ++q) {
      int src = lst2[base + min(i + q, c0)].x;
      s[q] = xws[(size_t)src * 64 + j];
    }
#pragma unroll
    for (int q = 0; q < 16; ++q)
      acc += (i + q < cnt) ? s[q] : 0.f;
  }
  float act = fmaxf(fmaf(dis[n], acc, b[j]), 0.f);
  h0[(size_t)n * 64 + j] = act;
  hj_slice[(size_t)n * 192 + j] = act;
}

// ------- mean-pool (batch sorted -> binary search) + classifier -------
__global__ __launch_bounds__(192) void k_pool(
    const float* __restrict__ hj, const int* __restrict__ batch, int N,
    const float* __restrict__ w1, const float* __restrict__ b1,
    const float* __restrict__ w2, const float* __restrict__ b2,
    float* __restrict__ out) {
  __shared__ float pl[192];
  int g = blockIdx.x;
  int t = threadIdx.x;
  int lo = 0, hi = N;
  while (lo < hi) { int m = (lo + hi) >> 1; if (batch[m] < g) lo = m + 1; else hi = m; }
  int start = lo;
  hi = N;
  while (lo < hi) { int m = (lo + hi) >> 1; if (batch[m] < g + 1) lo = m + 1; else hi = m; }
  int end = lo;
  float s = 0.f;
  for (int r = start; r < end; ++r) s += hj[(size_t)r * 192 + t];
  int cnt = end - start;
  pl[t] = s / (float)(cnt > 0 ? cnt : 1);
  __syncthreads();
  if (t < 64) {
    float val = 0.f;
    if (t < 32) {
      float z = b1[t];
#pragma unroll 8
      for (int k = 0; k < 192; ++k) z = fmaf(pl[k], w1[k * 32 + t], z);
      z = fmaxf(z, 0.f);
      val = z * w2[t];
    }
#pragma unroll
    for (int off = 16; off > 0; off >>= 1) val += __shfl_down(val, off);
    if (t == 0) out[g] = val + b2[0];
  }
}

extern "C" void kernel_launch(void* const* d_in, const int* in_sizes, int n_in,
                              void* d_out, int out_size, void* d_ws, size_t ws_size,
                              hipStream_t stream) {
  const float* x      = (const float*)d_in[0];
  const float* ea     = (const float*)d_in[1];
  const float* node_w = (const float*)d_in[2];
  const float* node_b = (const float*)d_in[3];
  const float* edge_w = (const float*)d_in[4];
  const float* edge_b = (const float*)d_in[5];
  const float* conv_w = (const float*)d_in[6];
  const float* conv_b = (const float*)d_in[7];
  const float* w1     = (const float*)d_in[8];
  const float* b1     = (const float*)d_in[9];
  const float* w2     = (const float*)d_in[10];
  const float* b2     = (const float*)d_in[11];
  const int*   ei     = (const int*)d_in[12];
  const int*   batch  = (const int*)d_in[13];

  const int N = in_sizes[0] / 128;
  const int E = in_sizes[12] / 2;
  const int G = out_size;
  const int* erow = ei;
  const int* ecol = ei + E;

  float* ws = (float*)d_ws;
  size_t o = 0;
  float* h0    = ws + o; o += (size_t)N * 64;
  float* xws   = ws + o; o += (size_t)N * 64;
  float* hj    = ws + o; o += (size_t)N * 192;  // build scratch aliases its head
  float* dis   = ws + o; o += N;
  int* indeg   = (int*)(ws + o); o += N;
  int* outdeg  = (int*)(ws + o); o += N;
  int* offc    = (int*)(ws + o); o += N;
  int* offr    = (int*)(ws + o); o += N;
  int* chsum   = (int*)(ws + o); o += 128;
  int* chbase  = (int*)(ws + o); o += 128;
  int2* lst2   = (int2*)(ws + o); o += (size_t)2 * E;  // persistent (gathers)

  const int NB = (N + 255) >> 8;              // col/row buckets (<=512)
  const int NBLK = (E + EPB - 1) / EPB;       // binning blocks
  // aliases onto hj (all dead before first k_gather writes hj):
  unsigned long long* tmpc = (unsigned long long*)hj;          // E*8B
  unsigned int* tmpr = (unsigned int*)(hj + (size_t)2 * E);    // E*4B
  int* eidr  = (int*)(hj + (size_t)3 * E);                     // E*4B
  int* matc  = (int*)(hj + (size_t)4 * E);                     // NBLK*NB
  int* matr  = matc + (size_t)NBLK * NB;
  int* totc  = matr + (size_t)NBLK * NB;
  int* startc = totc + NB;
  int* totr  = startc + NB;
  int* startr = totr + NB;
  float* out = (float*)d_out;

  const int nch = (N + 1023) / 1024;
  dim3 b256(256);

  hipMemsetAsync(indeg, 0, (size_t)N * sizeof(int), stream);
  hipMemsetAsync(outdeg, 0, (size_t)N * sizeof(int), stream);

  k_embed<<<(N + 63) / 64, b256, 0, stream>>>(x, node_w, node_b, h0, N);
  k_count<<<(E + 255) / 256, b256, 0, stream>>>(erow, ecol, indeg, outdeg, E);
  k_scanA<<<nch, b256, 0, stream>>>(indeg, offc, chsum, N);
  k_scanB<<<1, dim3(128), 0, stream>>>(chsum, chbase, nch);
  k_scanC<<<(N + 255) / 256, b256, 0, stream>>>(offc, chbase, N);
  k_scanA<<<nch, b256, 0, stream>>>(outdeg, offr, chsum, N);
  k_scanB<<<1, dim3(128), 0, stream>>>(chsum, chbase, nch);
  k_scanC<<<(N + 255) / 256, b256, 0, stream>>>(offr, chbase, N);
  k_hist<<<NBLK, b256, 0, stream>>>(erow, ecol, matc, matr, E, NB);
  kB1<<<(NB + 255) / 256, b256, 0, stream>>>(matc, totc, NBLK, NB);
  kB1<<<(NB + 255) / 256, b256, 0, stream>>>(matr, totr, NBLK, NB);
  kB2<<<1, dim3(512), 0, stream>>>(totc, startc, NB);
  kB2<<<1, dim3(512), 0, stream>>>(totr, startr, NB);
  k_scat<<<NBLK, b256, 0, stream>>>(erow, ecol, matc, matr, startc, startr,
                                    tmpc, tmpr, E, NB);
  k_place_c<<<NB, b256, 0, stream>>>(tmpc, offc, lst2, N, E);
  k_place_r<<<NB, b256, 0, stream>>>(tmpr, offr, eidr, N, E);
  k_eembed<<<((size_t)N * 64 + 255) / 256, b256, 0, stream>>>(
      ea, lst2, eidr, offc, indeg, offr, outdeg, edge_w, edge_b, h0, dis, N);
  for (int l = 0; l < 3; ++l) {
    k_conv<<<(N + 63) / 64, b256, 0, stream>>>(
        h0, conv_w + (size_t)l * 64 * 64, dis, xws, N);
    k_gather<<<((size_t)N * 64 + 255) / 256, b256, 0, stream>>>(
        xws, dis, offc, indeg, lst2, conv_b + (size_t)l * 64,
        h0, hj + (size_t)l * 64, N);
  }
  k_pool<<<G, dim3(192), 0, stream>>>(hj, batch, N, w1, b1, w2, b2, out);
}

// Round 7
// 577.281 us; speedup vs baseline: 1.8248x; 1.2274x over previous
//
#include <hip/hip_runtime.h>
#include <math.h>

// GraphCNN v7:
//  - GEMMs (embed/conv) restructured: lane j keeps W column j in VGPRs
//    (static-unroll), row values broadcast from LDS via wave-uniform
//    ds_read_b128 -> zero per-FMA memory traffic (v6's k_embed was 13.7%
//    VALUBusy, stalled on in-loop weight s_loads).
//  - histogram scan parallelized: bucket-major matT + one block per bucket
//    (v6's kB1 was 2 blocks x 293 serial iters).
//  Assumes N <= 131072, E < 2^24, N < 2^17.

#define EPB 4096  // edges per binning block

// ------- node embed: out[n][j] = sum_k x[n][k] w[k][j] + b[j]  (K=128) -------
__global__ __launch_bounds__(256) void k_embed(
    const float* __restrict__ x, const float* __restrict__ w,
    const float* __restrict__ b, float* __restrict__ out, int N) {
  __shared__ __align__(16) float rl[64 * 128];
  const int t = threadIdx.x;
  const int j = t & 63;
  const int wv = t >> 6;
  const int base = blockIdx.x * 64;
  float wr[128];
#pragma unroll
  for (int k = 0; k < 128; ++k) wr[k] = w[k * 64 + j];
  const float bj = b[j];
#pragma unroll
  for (int it = 0; it < 8; ++it) {
    int lin = (t + it * 256) * 4;
    int r = lin >> 7, c = lin & 127;
    int row = base + r;
    float4 v = (row < N) ? *(const float4*)&x[(size_t)row * 128 + c]
                         : make_float4(0.f, 0.f, 0.f, 0.f);
    *(float4*)&rl[lin] = v;
  }
  __syncthreads();
  for (int r = wv; r < 64; r += 4) {
    int row = base + r;
    if (row >= N) break;
    float acc = bj;
#pragma unroll
    for (int k4 = 0; k4 < 32; ++k4) {
      float4 a = *(const float4*)&rl[r * 128 + k4 * 4];
      acc = fmaf(a.x, wr[k4 * 4 + 0], acc);
      acc = fmaf(a.y, wr[k4 * 4 + 1], acc);
      acc = fmaf(a.z, wr[k4 * 4 + 2], acc);
      acc = fmaf(a.w, wr[k4 * 4 + 3], acc);
    }
    out[(size_t)row * 64 + j] = acc;
  }
}

// ------- conv GEMM with dis-prescale: xws[n][j] = dis[n] * sum_k h[n][k] w[k][j] -------
__global__ __launch_bounds__(256) void k_conv(
    const float* __restrict__ hin, const float* __restrict__ w,
    const float* __restrict__ dis, float* __restrict__ xws, int N) {
  __shared__ __align__(16) float rl[64 * 64];
  const int t = threadIdx.x;
  const int j = t & 63;
  const int wv = t >> 6;
  const int base = blockIdx.x * 64;
  float wr[64];
#pragma unroll
  for (int k = 0; k < 64; ++k) wr[k] = w[k * 64 + j];
#pragma unroll
  for (int it = 0; it < 4; ++it) {
    int lin = (t + it * 256) * 4;
    int r = lin >> 6, c = lin & 63;
    int row = base + r;
    float4 v = (row < N) ? *(const float4*)&hin[(size_t)row * 64 + c]
                         : make_float4(0.f, 0.f, 0.f, 0.f);
    *(float4*)&rl[lin] = v;
  }
  __syncthreads();
  for (int r = wv; r < 64; r += 4) {
    int row = base + r;
    if (row >= N) break;
    float acc = 0.f;
#pragma unroll
    for (int k4 = 0; k4 < 16; ++k4) {
      float4 a = *(const float4*)&rl[r * 64 + k4 * 4];
      acc = fmaf(a.x, wr[k4 * 4 + 0], acc);
      acc = fmaf(a.y, wr[k4 * 4 + 1], acc);
      acc = fmaf(a.z, wr[k4 * 4 + 2], acc);
      acc = fmaf(a.w, wr[k4 * 4 + 3], acc);
    }
    xws[(size_t)row * 64 + j] = dis[row] * acc;
  }
}

// ------- degree counts -------
__global__ __launch_bounds__(256) void k_count(
    const int* __restrict__ erow, const int* __restrict__ ecol,
    int* indeg, int* outdeg, int E) {
  int e = blockIdx.x * 256 + threadIdx.x;
  if (e < E) {
    atomicAdd(&indeg[ecol[e]], 1);
    atomicAdd(&outdeg[erow[e]], 1);
  }
}

// ------- exclusive scan over nodes (3 kernels, chunk=1024) -------
__global__ __launch_bounds__(256) void k_scanA(
    const int* __restrict__ cnt, int* __restrict__ off,
    int* __restrict__ chunk_sum, int N) {
  __shared__ int sc[256];
  int b = blockIdx.x, t = threadIdx.x;
  int i0 = b * 1024 + t * 4;
  int v[4];
  int s = 0;
#pragma unroll
  for (int q = 0; q < 4; ++q) {
    v[q] = (i0 + q < N) ? cnt[i0 + q] : 0;
    s += v[q];
  }
  sc[t] = s;
  __syncthreads();
  for (int d = 1; d < 256; d <<= 1) {
    int x = (t >= d) ? sc[t - d] : 0;
    __syncthreads();
    sc[t] += x;
    __syncthreads();
  }
  int run = sc[t] - s;
#pragma unroll
  for (int q = 0; q < 4; ++q) {
    if (i0 + q < N) off[i0 + q] = run;
    run += v[q];
  }
  if (t == 255) chunk_sum[b] = sc[255];
}

__global__ __launch_bounds__(128) void k_scanB(
    const int* __restrict__ chunk_sum, int* __restrict__ chunk_base, int nch) {
  __shared__ int sc[128];
  int t = threadIdx.x;
  int s = (t < nch) ? chunk_sum[t] : 0;
  sc[t] = s;
  __syncthreads();
  for (int d = 1; d < 128; d <<= 1) {
    int x = (t >= d) ? sc[t - d] : 0;
    __syncthreads();
    sc[t] += x;
    __syncthreads();
  }
  if (t < nch) chunk_base[t] = sc[t] - s;
}

__global__ __launch_bounds__(256) void k_scanC(
    int* __restrict__ off, const int* __restrict__ chunk_base, int N) {
  int i = blockIdx.x * 256 + threadIdx.x;
  if (i < N) off[i] += chunk_base[i >> 10];
}

// ------- per-block bucket histograms, bucket-major: matT[bucket*NBLK + blk] -------
__global__ __launch_bounds__(256) void k_hist(
    const int* __restrict__ erow, const int* __restrict__ ecol,
    int* __restrict__ matTc, int* __restrict__ matTr, int E, int NB, int NBLK) {
  __shared__ int hc[512], hr[512];
  int b = blockIdx.x, t = threadIdx.x;
  for (int i = t; i < NB; i += 256) { hc[i] = 0; hr[i] = 0; }
  __syncthreads();
  int e0 = b * EPB;
#pragma unroll
  for (int q = 0; q < 16; ++q) {
    int e = e0 + q * 256 + t;
    if (e < E) {
      atomicAdd(&hc[ecol[e] >> 8], 1);
      atomicAdd(&hr[erow[e] >> 8], 1);
    }
  }
  __syncthreads();
  for (int i = t; i < NB; i += 256) {
    matTc[(size_t)i * NBLK + b] = hc[i];
    matTr[(size_t)i * NBLK + b] = hr[i];
  }
}

// ------- per-bucket scan over blocks (block = bucket); also bucket totals -------
__global__ __launch_bounds__(256) void kBscan(
    int* __restrict__ matT, int* __restrict__ tot, int NBLK) {
  __shared__ int sc[256];
  int i = blockIdx.x, t = threadIdx.x;
  int* row = matT + (size_t)i * NBLK;
  int e0 = (2 * t < NBLK) ? row[2 * t] : 0;
  int e1 = (2 * t + 1 < NBLK) ? row[2 * t + 1] : 0;
  int s = e0 + e1;
  sc[t] = s;
  __syncthreads();
  for (int d = 1; d < 256; d <<= 1) {
    int x = (t >= d) ? sc[t - d] : 0;
    __syncthreads();
    sc[t] += x;
    __syncthreads();
  }
  int excl = sc[t] - s;
  if (2 * t < NBLK) row[2 * t] = excl;
  if (2 * t + 1 < NBLK) row[2 * t + 1] = excl + e0;
  if (t == 255) tot[i] = sc[255];
}

// ------- exclusive scan of bucket totals -> bucket starts (NB <= 512) -------
__global__ __launch_bounds__(512) void kB2(
    const int* __restrict__ tot, int* __restrict__ start, int NB) {
  __shared__ int sc[512];
  int t = threadIdx.x;
  int s = (t < NB) ? tot[t] : 0;
  sc[t] = s;
  __syncthreads();
  for (int d = 1; d < 512; d <<= 1) {
    int x = (t >= d) ? sc[t - d] : 0;
    __syncthreads();
    sc[t] += x;
    __syncthreads();
  }
  if (t < NB) start[t] = sc[t] - s;
}

// ------- scatter into bucket regions; LDS cursors, no global atomics -------
__global__ __launch_bounds__(256) void k_scat(
    const int* __restrict__ erow, const int* __restrict__ ecol,
    const int* __restrict__ matTc, const int* __restrict__ matTr,
    const int* __restrict__ startc, const int* __restrict__ startr,
    unsigned long long* __restrict__ tmpc, unsigned int* __restrict__ tmpr,
    int E, int NB, int NBLK) {
  __shared__ int curc[512], curr[512];
  int b = blockIdx.x, t = threadIdx.x;
  for (int i = t; i < NB; i += 256) {
    curc[i] = startc[i] + matTc[(size_t)i * NBLK + b];
    curr[i] = startr[i] + matTr[(size_t)i * NBLK + b];
  }
  __syncthreads();
  int e0 = b * EPB;
#pragma unroll
  for (int q = 0; q < 16; ++q) {
    int e = e0 + q * 256 + t;
    if (e < E) {
      int r = erow[e], c = ecol[e];
      int pc = atomicAdd(&curc[c >> 8], 1);
      tmpc[pc] = (unsigned long long)(c & 255) |
                 ((unsigned long long)r << 8) |
                 ((unsigned long long)e << 25);
      int pr = atomicAdd(&curr[r >> 8], 1);
      tmpr[pr] = ((unsigned int)e << 8) | (unsigned int)(r & 255);
    }
  }
}

// ------- place by-col: ordered CSR {src, eid} via LDS per-node cursors -------
__global__ __launch_bounds__(256) void k_place_c(
    const unsigned long long* __restrict__ tmpc, const int* __restrict__ offc,
    int2* __restrict__ lst2, int N, int E) {
  __shared__ int cur[256];
  int b = blockIdx.x, t = threadIdx.x;
  int colbase = b << 8;
  int nb = min(256, N - colbase);
  if (t < nb) cur[t] = offc[colbase + t];
  __syncthreads();
  int bstart = offc[colbase];
  int bend = (colbase + 256 < N) ? offc[colbase + 256] : E;
  for (int idx = bstart + t; idx < bend; idx += 256) {
    unsigned long long v = tmpc[idx];
    int lc = (int)(v & 255);
    int src = (int)((v >> 8) & 0x1FFFF);
    int eid = (int)(v >> 25);
    int p = atomicAdd(&cur[lc], 1);
    int2 w; w.x = src; w.y = eid;
    lst2[p] = w;
  }
}

// ------- place by-row: eid list grouped by row -------
__global__ __launch_bounds__(256) void k_place_r(
    const unsigned int* __restrict__ tmpr, const int* __restrict__ offr,
    int* __restrict__ eidr, int N, int E) {
  __shared__ int cur[256];
  int b = blockIdx.x, t = threadIdx.x;
  int rowbase = b << 8;
  int nb = min(256, N - rowbase);
  if (t < nb) cur[t] = offr[rowbase + t];
  __syncthreads();
  int bstart = offr[rowbase];
  int bend = (rowbase + 256 < N) ? offr[rowbase + 256] : E;
  for (int idx = bstart + t; idx < bend; idx += 256) {
    unsigned int v = tmpr[idx];
    int lr = (int)(v & 255);
    int p = atomicAdd(&cur[lr], 1);
    eidr[p] = (int)(v >> 8);
  }
}

// ------- fused edge embed: gather ea over incident edges, 16->64 GEMM, dis -------
__global__ __launch_bounds__(256) void k_eembed(
    const float* __restrict__ ea, const int2* __restrict__ lst2,
    const int* __restrict__ eidr, const int* __restrict__ offc,
    const int* __restrict__ indeg, const int* __restrict__ offr,
    const int* __restrict__ outdeg, const float* __restrict__ ew,
    const float* __restrict__ eb, float* h0, float* __restrict__ dis, int N) {
  int t = blockIdx.x * 256 + threadIdx.x;
  int n = __builtin_amdgcn_readfirstlane(t >> 6);
  if (n >= N) return;
  int lane = threadIdx.x & 63;
  int slot = lane >> 4, kk = lane & 15;
  int cin = indeg[n], basec = offc[n];
  int cout = outdeg[n], baser = offr[n];
  float acc = 0.f;
  int c0 = (cin > 0) ? cin - 1 : 0;
  for (int i = 0; i < cin; i += 16) {
#pragma unroll
    for (int q = 0; q < 4; ++q) {
      int idx = i + q * 4 + slot;
      int eid = lst2[basec + min(idx, c0)].y;
      float v = ea[(size_t)eid * 16 + kk];
      acc += (idx < cin) ? v : 0.f;
    }
  }
  int r0 = (cout > 0) ? cout - 1 : 0;
  for (int i = 0; i < cout; i += 16) {
#pragma unroll
    for (int q = 0; q < 4; ++q) {
      int idx = i + q * 4 + slot;
      int eid = eidr[baser + min(idx, r0)];
      float v = ea[(size_t)eid * 16 + kk];
      acc += (idx < cout) ? v : 0.f;
    }
  }
  acc += __shfl_xor(acc, 16, 64);
  acc += __shfl_xor(acc, 32, 64);
  int j = lane;
  float v = h0[(size_t)n * 64 + j] + (float)(cin + cout) * eb[j];
#pragma unroll
  for (int k = 0; k < 16; ++k) {
    float ak = __shfl(acc, k, 64);
    v = fmaf(ak, ew[k * 64 + j], v);
  }
  h0[(size_t)n * 64 + j] = v;
  if (j == 0) dis[n] = 1.0f / sqrtf((float)cin + 1.0f);
}

// ------- gather: h_new = relu( dis_n * (xws[n] + sum_src xws[src]) + b ) -------
__global__ __launch_bounds__(256) void k_gather(
    const float* __restrict__ xws, const float* __restrict__ dis,
    const int* __restrict__ offc, const int* __restrict__ indeg,
    const int2* __restrict__ lst2, const float* __restrict__ b,
    float* __restrict__ h0, float* __restrict__ hj_slice, int N) {
  int t = blockIdx.x * 256 + threadIdx.x;
  int j = t & 63;
  int n = __builtin_amdgcn_readfirstlane(t >> 6);
  if (n >= N) return;
  int cnt = indeg[n];
  int base = offc[n];
  int c0 = (cnt > 0) ? cnt - 1 : 0;
  float acc = xws[(size_t)n * 64 + j];
  for (int i = 0; i < cnt; i += 16) {
    float s[16];
#pragma unroll
    for (int q = 0; q < 16; ++q) {
      int src = lst2[base + min(i + q, c0)].x;
      s[q] = xws[(size_t)src * 64 + j];
    }
#pragma unroll
    for (int q = 0; q < 16; ++q)
      acc += (i + q < cnt) ? s[q] : 0.f;
  }
  float act = fmaxf(fmaf(dis[n], acc, b[j]), 0.f);
  h0[(size_t)n * 64 + j] = act;
  hj_slice[(size_t)n * 192 + j] = act;
}

// ------- mean-pool (batch sorted -> binary search) + classifier -------
__global__ __launch_bounds__(192) void k_pool(
    const float* __restrict__ hj, const int* __restrict__ batch, int N,
    const float* __restrict__ w1, const float* __restrict__ b1,
    const float* __restrict__ w2, const float* __restrict__ b2,
    float* __restrict__ out) {
  __shared__ float pl[192];
  int g = blockIdx.x;
  int t = threadIdx.x;
  int lo = 0, hi = N;
  while (lo < hi) { int m = (lo + hi) >> 1; if (batch[m] < g) lo = m + 1; else hi = m; }
  int start = lo;
  hi = N;
  while (lo < hi) { int m = (lo + hi) >> 1; if (batch[m] < g + 1) lo = m + 1; else hi = m; }
  int end = lo;
  float s = 0.f;
  for (int r = start; r < end; ++r) s += hj[(size_t)r * 192 + t];
  int cnt = end - start;
  pl[t] = s / (float)(cnt > 0 ? cnt : 1);
  __syncthreads();
  if (t < 64) {
    float val = 0.f;
    if (t < 32) {
      float z = b1[t];
#pragma unroll 8
      for (int k = 0; k < 192; ++k) z = fmaf(pl[k], w1[k * 32 + t], z);
      z = fmaxf(z, 0.f);
      val = z * w2[t];
    }
#pragma unroll
    for (int off = 16; off > 0; off >>= 1) val += __shfl_down(val, off);
    if (t == 0) out[g] = val + b2[0];
  }
}

extern "C" void kernel_launch(void* const* d_in, const int* in_sizes, int n_in,
                              void* d_out, int out_size, void* d_ws, size_t ws_size,
                              hipStream_t stream) {
  const float* x      = (const float*)d_in[0];
  const float* ea     = (const float*)d_in[1];
  const float* node_w = (const float*)d_in[2];
  const float* node_b = (const float*)d_in[3];
  const float* edge_w = (const float*)d_in[4];
  const float* edge_b = (const float*)d_in[5];
  const float* conv_w = (const float*)d_in[6];
  const float* conv_b = (const float*)d_in[7];
  const float* w1     = (const float*)d_in[8];
  const float* b1     = (const float*)d_in[9];
  const float* w2     = (const float*)d_in[10];
  const float* b2     = (const float*)d_in[11];
  const int*   ei     = (const int*)d_in[12];
  const int*   batch  = (const int*)d_in[13];

  const int N = in_sizes[0] / 128;
  const int E = in_sizes[12] / 2;
  const int G = out_size;
  const int* erow = ei;
  const int* ecol = ei + E;

  float* ws = (float*)d_ws;
  size_t o = 0;
  float* h0    = ws + o; o += (size_t)N * 64;
  float* xws   = ws + o; o += (size_t)N * 64;
  float* hj    = ws + o; o += (size_t)N * 192;  // build scratch aliases its head
  float* dis   = ws + o; o += N;
  int* indeg   = (int*)(ws + o); o += N;
  int* outdeg  = (int*)(ws + o); o += N;
  int* offc    = (int*)(ws + o); o += N;
  int* offr    = (int*)(ws + o); o += N;
  int* chsum   = (int*)(ws + o); o += 128;
  int* chbase  = (int*)(ws + o); o += 128;
  int2* lst2   = (int2*)(ws + o); o += (size_t)2 * E;  // persistent (gathers)

  const int NB = (N + 255) >> 8;              // buckets (<=512)
  const int NBLK = (E + EPB - 1) / EPB;       // binning blocks
  // aliases onto hj (all dead before first k_gather writes hj):
  unsigned long long* tmpc = (unsigned long long*)hj;          // E*8B
  unsigned int* tmpr = (unsigned int*)(hj + (size_t)2 * E);    // E*4B
  int* eidr  = (int*)(hj + (size_t)3 * E);                     // E*4B
  int* matTc = (int*)(hj + (size_t)4 * E);                     // NB*NBLK
  int* matTr = matTc + (size_t)NB * NBLK;
  int* totc  = matTr + (size_t)NB * NBLK;
  int* startc = totc + NB;
  int* totr  = startc + NB;
  int* startr = totr + NB;
  float* out = (float*)d_out;

  const int nch = (N + 1023) / 1024;
  dim3 b256(256);

  hipMemsetAsync(indeg, 0, (size_t)N * sizeof(int), stream);
  hipMemsetAsync(outdeg, 0, (size_t)N * sizeof(int), stream);

  k_embed<<<(N + 63) / 64, b256, 0, stream>>>(x, node_w, node_b, h0, N);
  k_count<<<(E + 255) / 256, b256, 0, stream>>>(erow, ecol, indeg, outdeg, E);
  k_scanA<<<nch, b256, 0, stream>>>(indeg, offc, chsum, N);
  k_scanB<<<1, dim3(128), 0, stream>>>(chsum, chbase, nch);
  k_scanC<<<(N + 255) / 256, b256, 0, stream>>>(offc, chbase, N);
  k_scanA<<<nch, b256, 0, stream>>>(outdeg, offr, chsum, N);
  k_scanB<<<1, dim3(128), 0, stream>>>(chsum, chbase, nch);
  k_scanC<<<(N + 255) / 256, b256, 0, stream>>>(offr, chbase, N);
  k_hist<<<NBLK, b256, 0, stream>>>(erow, ecol, matTc, matTr, E, NB, NBLK);
  kBscan<<<NB, b256, 0, stream>>>(matTc, totc, NBLK);
  kBscan<<<NB, b256, 0, stream>>>(matTr, totr, NBLK);
  kB2<<<1, dim3(512), 0, stream>>>(totc, startc, NB);
  kB2<<<1, dim3(512), 0, stream>>>(totr, startr, NB);
  k_scat<<<NBLK, b256, 0, stream>>>(erow, ecol, matTc, matTr, startc, startr,
                                    tmpc, tmpr, E, NB, NBLK);
  k_place_c<<<NB, b256, 0, stream>>>(tmpc, offc, lst2, N, E);
  k_place_r<<<NB, b256, 0, stream>>>(tmpr, offr, eidr, N, E);
  k_eembed<<<((size_t)N * 64 + 255) / 256, b256, 0, stream>>>(
      ea, lst2, eidr, offc, indeg, offr, outdeg, edge_w, edge_b, h0, dis, N);
  for (int l = 0; l < 3; ++l) {
    k_conv<<<(N + 63) / 64, b256, 0, stream>>>(
        h0, conv_w + (size_t)l * 64 * 64, dis, xws, N);
    k_gather<<<((size_t)N * 64 + 255) / 256, b256, 0, stream>>>(
        xws, dis, offc, indeg, lst2, conv_b + (size_t)l * 64,
        h0, hj + (size_t)l * 64, N);
  }
  k_pool<<<G, dim3(192), 0, stream>>>(hj, batch, N, w1, b1, w2, b2, out);
}

// Round 8
// 472.993 us; speedup vs baseline: 2.2272x; 1.2205x over previous
//
#include <hip/hip_runtime.h>
#include <math.h>

// GraphCNN v8: zero global atomics anywhere.
//  v7 lesson: k_count's 2.4M scattered global atomics = 94us with 74MB
//  writeback (31B/atomic at the coherence point). v8 derives indeg/outdeg +
//  CSR offsets from the bucketed tmp arrays via per-bucket LDS histograms +
//  LDS scans (k_bcount_*), deleting k_count and the 6-launch scan chain.
//  Assumes N <= 131072 (NB <= 512), E < 2^24, N < 2^17.

#define EPB 4096  // edges per binning block

// ------- node embed: out[n][j] = sum_k x[n][k] w[k][j] + b[j]  (K=128) -------
__global__ __launch_bounds__(256) void k_embed(
    const float* __restrict__ x, const float* __restrict__ w,
    const float* __restrict__ b, float* __restrict__ out, int N) {
  __shared__ __align__(16) float rl[64 * 128];
  const int t = threadIdx.x;
  const int j = t & 63;
  const int wv = t >> 6;
  const int base = blockIdx.x * 64;
  float wr[128];
#pragma unroll
  for (int k = 0; k < 128; ++k) wr[k] = w[k * 64 + j];
  const float bj = b[j];
#pragma unroll
  for (int it = 0; it < 8; ++it) {
    int lin = (t + it * 256) * 4;
    int r = lin >> 7, c = lin & 127;
    int row = base + r;
    float4 v = (row < N) ? *(const float4*)&x[(size_t)row * 128 + c]
                         : make_float4(0.f, 0.f, 0.f, 0.f);
    *(float4*)&rl[lin] = v;
  }
  __syncthreads();
  for (int r = wv; r < 64; r += 4) {
    int row = base + r;
    if (row >= N) break;
    float acc = bj;
#pragma unroll
    for (int k4 = 0; k4 < 32; ++k4) {
      float4 a = *(const float4*)&rl[r * 128 + k4 * 4];
      acc = fmaf(a.x, wr[k4 * 4 + 0], acc);
      acc = fmaf(a.y, wr[k4 * 4 + 1], acc);
      acc = fmaf(a.z, wr[k4 * 4 + 2], acc);
      acc = fmaf(a.w, wr[k4 * 4 + 3], acc);
    }
    out[(size_t)row * 64 + j] = acc;
  }
}

// ------- conv GEMM with dis-prescale: xws[n][j] = dis[n]*sum_k h[n][k] w[k][j] -------
__global__ __launch_bounds__(256) void k_conv(
    const float* __restrict__ hin, const float* __restrict__ w,
    const float* __restrict__ dis, float* __restrict__ xws, int N) {
  __shared__ __align__(16) float rl[64 * 64];
  const int t = threadIdx.x;
  const int j = t & 63;
  const int wv = t >> 6;
  const int base = blockIdx.x * 64;
  float wr[64];
#pragma unroll
  for (int k = 0; k < 64; ++k) wr[k] = w[k * 64 + j];
#pragma unroll
  for (int it = 0; it < 4; ++it) {
    int lin = (t + it * 256) * 4;
    int r = lin >> 6, c = lin & 63;
    int row = base + r;
    float4 v = (row < N) ? *(const float4*)&hin[(size_t)row * 64 + c]
                         : make_float4(0.f, 0.f, 0.f, 0.f);
    *(float4*)&rl[lin] = v;
  }
  __syncthreads();
  for (int r = wv; r < 64; r += 4) {
    int row = base + r;
    if (row >= N) break;
    float acc = 0.f;
#pragma unroll
    for (int k4 = 0; k4 < 16; ++k4) {
      float4 a = *(const float4*)&rl[r * 64 + k4 * 4];
      acc = fmaf(a.x, wr[k4 * 4 + 0], acc);
      acc = fmaf(a.y, wr[k4 * 4 + 1], acc);
      acc = fmaf(a.z, wr[k4 * 4 + 2], acc);
      acc = fmaf(a.w, wr[k4 * 4 + 3], acc);
    }
    xws[(size_t)row * 64 + j] = dis[row] * acc;
  }
}

// ------- per-block bucket histograms, bucket-major: matT[bucket*NBLK + blk] -------
__global__ __launch_bounds__(256) void k_hist(
    const int* __restrict__ erow, const int* __restrict__ ecol,
    int* __restrict__ matTc, int* __restrict__ matTr, int E, int NB, int NBLK) {
  __shared__ int hc[512], hr[512];
  int b = blockIdx.x, t = threadIdx.x;
  for (int i = t; i < NB; i += 256) { hc[i] = 0; hr[i] = 0; }
  __syncthreads();
  int e0 = b * EPB;
#pragma unroll
  for (int q = 0; q < 16; ++q) {
    int e = e0 + q * 256 + t;
    if (e < E) {
      atomicAdd(&hc[ecol[e] >> 8], 1);
      atomicAdd(&hr[erow[e] >> 8], 1);
    }
  }
  __syncthreads();
  for (int i = t; i < NB; i += 256) {
    matTc[(size_t)i * NBLK + b] = hc[i];
    matTr[(size_t)i * NBLK + b] = hr[i];
  }
}

// ------- per-bucket scan over blocks (block = bucket); bucket totals -------
__global__ __launch_bounds__(256) void kBscan(
    int* __restrict__ matT, int* __restrict__ tot, int NBLK) {
  __shared__ int sc[256];
  int i = blockIdx.x, t = threadIdx.x;
  int* row = matT + (size_t)i * NBLK;
  int e0 = (2 * t < NBLK) ? row[2 * t] : 0;
  int e1 = (2 * t + 1 < NBLK) ? row[2 * t + 1] : 0;
  int s = e0 + e1;
  sc[t] = s;
  __syncthreads();
  for (int d = 1; d < 256; d <<= 1) {
    int x = (t >= d) ? sc[t - d] : 0;
    __syncthreads();
    sc[t] += x;
    __syncthreads();
  }
  int excl = sc[t] - s;
  if (2 * t < NBLK) row[2 * t] = excl;
  if (2 * t + 1 < NBLK) row[2 * t + 1] = excl + e0;
  if (t == 255) tot[i] = sc[255];
}

// ------- exclusive scan of bucket totals -> bucket starts (NB <= 512) -------
__global__ __launch_bounds__(512) void kB2(
    const int* __restrict__ tot, int* __restrict__ start, int NB) {
  __shared__ int sc[512];
  int t = threadIdx.x;
  int s = (t < NB) ? tot[t] : 0;
  sc[t] = s;
  __syncthreads();
  for (int d = 1; d < 512; d <<= 1) {
    int x = (t >= d) ? sc[t - d] : 0;
    __syncthreads();
    sc[t] += x;
    __syncthreads();
  }
  if (t < NB) start[t] = sc[t] - s;
}

// ------- scatter into bucket regions; LDS cursors, no global atomics -------
__global__ __launch_bounds__(256) void k_scat(
    const int* __restrict__ erow, const int* __restrict__ ecol,
    const int* __restrict__ matTc, const int* __restrict__ matTr,
    const int* __restrict__ startc, const int* __restrict__ startr,
    unsigned long long* __restrict__ tmpc, unsigned int* __restrict__ tmpr,
    int E, int NB, int NBLK) {
  __shared__ int curc[512], curr[512];
  int b = blockIdx.x, t = threadIdx.x;
  for (int i = t; i < NB; i += 256) {
    curc[i] = startc[i] + matTc[(size_t)i * NBLK + b];
    curr[i] = startr[i] + matTr[(size_t)i * NBLK + b];
  }
  __syncthreads();
  int e0 = b * EPB;
#pragma unroll
  for (int q = 0; q < 16; ++q) {
    int e = e0 + q * 256 + t;
    if (e < E) {
      int r = erow[e], c = ecol[e];
      int pc = atomicAdd(&curc[c >> 8], 1);
      tmpc[pc] = (unsigned long long)(c & 255) |
                 ((unsigned long long)r << 8) |
                 ((unsigned long long)e << 25);
      int pr = atomicAdd(&curr[r >> 8], 1);
      tmpr[pr] = ((unsigned int)e << 8) | (unsigned int)(r & 255);
    }
  }
}

// ------- per-bucket node degree + CSR offset from tmpc (col side) -------
__global__ __launch_bounds__(256) void k_bcount_c(
    const unsigned long long* __restrict__ tmpc, const int* __restrict__ startc,
    const int* __restrict__ totc, int* __restrict__ indeg,
    int* __restrict__ offc, int N) {
  __shared__ int h[256], sc[256];
  int b = blockIdx.x, t = threadIdx.x;
  h[t] = 0;
  __syncthreads();
  int bstart = startc[b], cnt = totc[b];
  for (int i = t; i < cnt; i += 256)
    atomicAdd(&h[(int)(tmpc[bstart + i] & 255)], 1);
  __syncthreads();
  int s = h[t];
  sc[t] = s;
  __syncthreads();
  for (int d = 1; d < 256; d <<= 1) {
    int x = (t >= d) ? sc[t - d] : 0;
    __syncthreads();
    sc[t] += x;
    __syncthreads();
  }
  int n = (b << 8) + t;
  if (n < N) {
    indeg[n] = s;
    offc[n] = bstart + sc[t] - s;
  }
}

// ------- per-bucket node degree + CSR offset from tmpr (row side) -------
__global__ __launch_bounds__(256) void k_bcount_r(
    const unsigned int* __restrict__ tmpr, const int* __restrict__ startr,
    const int* __restrict__ totr, int* __restrict__ outdeg,
    int* __restrict__ offr, int N) {
  __shared__ int h[256], sc[256];
  int b = blockIdx.x, t = threadIdx.x;
  h[t] = 0;
  __syncthreads();
  int bstart = startr[b], cnt = totr[b];
  for (int i = t; i < cnt; i += 256)
    atomicAdd(&h[(int)(tmpr[bstart + i] & 255)], 1);
  __syncthreads();
  int s = h[t];
  sc[t] = s;
  __syncthreads();
  for (int d = 1; d < 256; d <<= 1) {
    int x = (t >= d) ? sc[t - d] : 0;
    __syncthreads();
    sc[t] += x;
    __syncthreads();
  }
  int n = (b << 8) + t;
  if (n < N) {
    outdeg[n] = s;
    offr[n] = bstart + sc[t] - s;
  }
}

// ------- place by-col: ordered CSR {src, eid} via LDS per-node cursors -------
__global__ __launch_bounds__(256) void k_place_c(
    const unsigned long long* __restrict__ tmpc, const int* __restrict__ offc,
    int2* __restrict__ lst2, int N, int E) {
  __shared__ int cur[256];
  int b = blockIdx.x, t = threadIdx.x;
  int colbase = b << 8;
  int nb = min(256, N - colbase);
  if (t < nb) cur[t] = offc[colbase + t];
  __syncthreads();
  int bstart = offc[colbase];
  int bend = (colbase + 256 < N) ? offc[colbase + 256] : E;
  for (int idx = bstart + t; idx < bend; idx += 256) {
    unsigned long long v = tmpc[idx];
    int lc = (int)(v & 255);
    int src = (int)((v >> 8) & 0x1FFFF);
    int eid = (int)(v >> 25);
    int p = atomicAdd(&cur[lc], 1);
    int2 w; w.x = src; w.y = eid;
    lst2[p] = w;
  }
}

// ------- place by-row: eid list grouped by row -------
__global__ __launch_bounds__(256) void k_place_r(
    const unsigned int* __restrict__ tmpr, const int* __restrict__ offr,
    int* __restrict__ eidr, int N, int E) {
  __shared__ int cur[256];
  int b = blockIdx.x, t = threadIdx.x;
  int rowbase = b << 8;
  int nb = min(256, N - rowbase);
  if (t < nb) cur[t] = offr[rowbase + t];
  __syncthreads();
  int bstart = offr[rowbase];
  int bend = (rowbase + 256 < N) ? offr[rowbase + 256] : E;
  for (int idx = bstart + t; idx < bend; idx += 256) {
    unsigned int v = tmpr[idx];
    int lr = (int)(v & 255);
    int p = atomicAdd(&cur[lr], 1);
    eidr[p] = (int)(v >> 8);
  }
}

// ------- fused edge embed: gather ea over incident edges, 16->64 GEMM, dis -------
__global__ __launch_bounds__(256) void k_eembed(
    const float* __restrict__ ea, const int2* __restrict__ lst2,
    const int* __restrict__ eidr, const int* __restrict__ offc,
    const int* __restrict__ indeg, const int* __restrict__ offr,
    const int* __restrict__ outdeg, const float* __restrict__ ew,
    const float* __restrict__ eb, float* h0, float* __restrict__ dis, int N) {
  int t = blockIdx.x * 256 + threadIdx.x;
  int n = __builtin_amdgcn_readfirstlane(t >> 6);
  if (n >= N) return;
  int lane = threadIdx.x & 63;
  int slot = lane >> 4, kk = lane & 15;
  int cin = indeg[n], basec = offc[n];
  int cout = outdeg[n], baser = offr[n];
  float acc = 0.f;
  int c0 = (cin > 0) ? cin - 1 : 0;
  for (int i = 0; i < cin; i += 16) {
#pragma unroll
    for (int q = 0; q < 4; ++q) {
      int idx = i + q * 4 + slot;
      int eid = lst2[basec + min(idx, c0)].y;
      float v = ea[(size_t)eid * 16 + kk];
      acc += (idx < cin) ? v : 0.f;
    }
  }
  int r0 = (cout > 0) ? cout - 1 : 0;
  for (int i = 0; i < cout; i += 16) {
#pragma unroll
    for (int q = 0; q < 4; ++q) {
      int idx = i + q * 4 + slot;
      int eid = eidr[baser + min(idx, r0)];
      float v = ea[(size_t)eid * 16 + kk];
      acc += (idx < cout) ? v : 0.f;
    }
  }
  acc += __shfl_xor(acc, 16, 64);
  acc += __shfl_xor(acc, 32, 64);
  int j = lane;
  float v = h0[(size_t)n * 64 + j] + (float)(cin + cout) * eb[j];
#pragma unroll
  for (int k = 0; k < 16; ++k) {
    float ak = __shfl(acc, k, 64);
    v = fmaf(ak, ew[k * 64 + j], v);
  }
  h0[(size_t)n * 64 + j] = v;
  if (j == 0) dis[n] = 1.0f / sqrtf((float)cin + 1.0f);
}

// ------- gather: h_new = relu( dis_n * (xws[n] + sum_src xws[src]) + b ) -------
__global__ __launch_bounds__(256) void k_gather(
    const float* __restrict__ xws, const float* __restrict__ dis,
    const int* __restrict__ offc, const int* __restrict__ indeg,
    const int2* __restrict__ lst2, const float* __restrict__ b,
    float* __restrict__ h0, float* __restrict__ hj_slice, int N) {
  int t = blockIdx.x * 256 + threadIdx.x;
  int j = t & 63;
  int n = __builtin_amdgcn_readfirstlane(t >> 6);
  if (n >= N) return;
  int cnt = indeg[n];
  int base = offc[n];
  int c0 = (cnt > 0) ? cnt - 1 : 0;
  float acc = xws[(size_t)n * 64 + j];
  for (int i = 0; i < cnt; i += 16) {
    float s[16];
#pragma unroll
    for (int q = 0; q < 16; ++q) {
      int src = lst2[base + min(i + q, c0)].x;
      s[q] = xws[(size_t)src * 64 + j];
    }
#pragma unroll
    for (int q = 0; q < 16; ++q)
      acc += (i + q < cnt) ? s[q] : 0.f;
  }
  float act = fmaxf(fmaf(dis[n], acc, b[j]), 0.f);
  h0[(size_t)n * 64 + j] = act;
  hj_slice[(size_t)n * 192 + j] = act;
}

// ------- mean-pool (batch sorted -> binary search) + classifier -------
__global__ __launch_bounds__(192) void k_pool(
    const float* __restrict__ hj, const int* __restrict__ batch, int N,
    const float* __restrict__ w1, const float* __restrict__ b1,
    const float* __restrict__ w2, const float* __restrict__ b2,
    float* __restrict__ out) {
  __shared__ float pl[192];
  int g = blockIdx.x;
  int t = threadIdx.x;
  int lo = 0, hi = N;
  while (lo < hi) { int m = (lo + hi) >> 1; if (batch[m] < g) lo = m + 1; else hi = m; }
  int start = lo;
  hi = N;
  while (lo < hi) { int m = (lo + hi) >> 1; if (batch[m] < g + 1) lo = m + 1; else hi = m; }
  int end = lo;
  float s = 0.f;
  for (int r = start; r < end; ++r) s += hj[(size_t)r * 192 + t];
  int cnt = end - start;
  pl[t] = s / (float)(cnt > 0 ? cnt : 1);
  __syncthreads();
  if (t < 64) {
    float val = 0.f;
    if (t < 32) {
      float z = b1[t];
#pragma unroll 8
      for (int k = 0; k < 192; ++k) z = fmaf(pl[k], w1[k * 32 + t], z);
      z = fmaxf(z, 0.f);
      val = z * w2[t];
    }
#pragma unroll
    for (int off = 16; off > 0; off >>= 1) val += __shfl_down(val, off);
    if (t == 0) out[g] = val + b2[0];
  }
}

extern "C" void kernel_launch(void* const* d_in, const int* in_sizes, int n_in,
                              void* d_out, int out_size, void* d_ws, size_t ws_size,
                              hipStream_t stream) {
  const float* x      = (const float*)d_in[0];
  const float* ea     = (const float*)d_in[1];
  const float* node_w = (const float*)d_in[2];
  const float* node_b = (const float*)d_in[3];
  const float* edge_w = (const float*)d_in[4];
  const float* edge_b = (const float*)d_in[5];
  const float* conv_w = (const float*)d_in[6];
  const float* conv_b = (const float*)d_in[7];
  const float* w1     = (const float*)d_in[8];
  const float* b1     = (const float*)d_in[9];
  const float* w2     = (const float*)d_in[10];
  const float* b2     = (const float*)d_in[11];
  const int*   ei     = (const int*)d_in[12];
  const int*   batch  = (const int*)d_in[13];

  const int N = in_sizes[0] / 128;
  const int E = in_sizes[12] / 2;
  const int G = out_size;
  const int* erow = ei;
  const int* ecol = ei + E;

  float* ws = (float*)d_ws;
  size_t o = 0;
  float* h0    = ws + o; o += (size_t)N * 64;
  float* xws   = ws + o; o += (size_t)N * 64;
  float* hj    = ws + o; o += (size_t)N * 192;  // build scratch aliases its head
  float* dis   = ws + o; o += N;
  int* indeg   = (int*)(ws + o); o += N;
  int* outdeg  = (int*)(ws + o); o += N;
  int* offc    = (int*)(ws + o); o += N;
  int* offr    = (int*)(ws + o); o += N;
  int2* lst2   = (int2*)(ws + o); o += (size_t)2 * E;  // persistent (gathers)

  const int NB = (N + 255) >> 8;              // buckets (<=512)
  const int NBLK = (E + EPB - 1) / EPB;       // binning blocks
  // aliases onto hj (all dead before first k_gather writes hj):
  unsigned long long* tmpc = (unsigned long long*)hj;          // E*8B
  unsigned int* tmpr = (unsigned int*)(hj + (size_t)2 * E);    // E*4B
  int* eidr  = (int*)(hj + (size_t)3 * E);                     // E*4B
  int* matTc = (int*)(hj + (size_t)4 * E);                     // NB*NBLK
  int* matTr = matTc + (size_t)NB * NBLK;
  int* totc  = matTr + (size_t)NB * NBLK;
  int* startc = totc + NB;
  int* totr  = startc + NB;
  int* startr = totr + NB;
  float* out = (float*)d_out;

  dim3 b256(256);

  k_embed<<<(N + 63) / 64, b256, 0, stream>>>(x, node_w, node_b, h0, N);
  k_hist<<<NBLK, b256, 0, stream>>>(erow, ecol, matTc, matTr, E, NB, NBLK);
  kBscan<<<NB, b256, 0, stream>>>(matTc, totc, NBLK);
  kBscan<<<NB, b256, 0, stream>>>(matTr, totr, NBLK);
  kB2<<<1, dim3(512), 0, stream>>>(totc, startc, NB);
  kB2<<<1, dim3(512), 0, stream>>>(totr, startr, NB);
  k_scat<<<NBLK, b256, 0, stream>>>(erow, ecol, matTc, matTr, startc, startr,
                                    tmpc, tmpr, E, NB, NBLK);
  k_bcount_c<<<NB, b256, 0, stream>>>(tmpc, startc, totc, indeg, offc, N);
  k_bcount_r<<<NB, b256, 0, stream>>>(tmpr, startr, totr, outdeg, offr, N);
  k_place_c<<<NB, b256, 0, stream>>>(tmpc, offc, lst2, N, E);
  k_place_r<<<NB, b256, 0, stream>>>(tmpr, offr, eidr, N, E);
  k_eembed<<<((size_t)N * 64 + 255) / 256, b256, 0, stream>>>(
      ea, lst2, eidr, offc, indeg, offr, outdeg, edge_w, edge_b, h0, dis, N);
  for (int l = 0; l < 3; ++l) {
    k_conv<<<(N + 63) / 64, b256, 0, stream>>>(
        h0, conv_w + (size_t)l * 64 * 64, dis, xws, N);
    k_gather<<<((size_t)N * 64 + 255) / 256, b256, 0, stream>>>(
        xws, dis, offc, indeg, lst2, conv_b + (size_t)l * 64,
        h0, hj + (size_t)l * 64, N);
  }
  k_pool<<<G, dim3(192), 0, stream>>>(hj, batch, N, w1, b1, w2, b2, out);
}